// Round 1
// baseline (604.012 us; speedup 1.0000x reference)
//
#include <hip/hip_runtime.h>

// TemporalUnfold1d: x (B, C, T) fp32 -> out (B, K*C, T), K=4, dilation=1,
// causal left pad of 3. out[b, kk*C + c, t] = x[b, c, t + kk - 3] (0 if OOB).
//
// Memory-bound: 128 MiB in + 512 MiB out. Strategy: one thread per float4 of
// one input row; build all 4 shifted windows in registers from two aligned
// float4 loads (prev float4 is the neighbor's data -> L1 hit, so HBM read
// stays ~1x input). All stores are aligned coalesced float4.

constexpr int K  = 4;
constexpr int C  = 256;
constexpr int T  = 8192;
constexpr int T4 = T / 4;   // 2048 float4s per row

__global__ __launch_bounds__(256) void TemporalUnfold1d_kernel(
    const float4* __restrict__ x4,
    float4* __restrict__ o4,
    int rows /* B*C */) {
    int gid = blockIdx.x * blockDim.x + threadIdx.x;
    int total = rows * T4;
    if (gid >= total) return;

    int row = gid >> 11;            // gid / T4  (T4 = 2048)
    int t4  = gid & (T4 - 1);       // gid % T4

    const float4* xrow = x4 + (size_t)row * T4;
    float4 cur  = xrow[t4];
    float4 prev = (t4 == 0) ? make_float4(0.f, 0.f, 0.f, 0.f) : xrow[t4 - 1];

    int b = row >> 8;               // row / C  (C = 256)
    int c = row & (C - 1);          // row % C

    // Output row index for kk: b*K*C + kk*C + c
    size_t obase = ((size_t)b * K) * C + c;

    float4 w0 = make_float4(prev.y, prev.z, prev.w, cur.x);  // shift -3
    float4 w1 = make_float4(prev.z, prev.w, cur.x, cur.y);   // shift -2
    float4 w2 = make_float4(prev.w, cur.x,  cur.y, cur.z);   // shift -1
    float4 w3 = cur;                                         // shift  0

    o4[(obase + 0 * (size_t)C) * T4 + t4] = w0;
    o4[(obase + 1 * (size_t)C) * T4 + t4] = w1;
    o4[(obase + 2 * (size_t)C) * T4 + t4] = w2;
    o4[(obase + 3 * (size_t)C) * T4 + t4] = w3;
}

extern "C" void kernel_launch(void* const* d_in, const int* in_sizes, int n_in,
                              void* d_out, int out_size, void* d_ws, size_t ws_size,
                              hipStream_t stream) {
    const float4* x4 = (const float4*)d_in[0];
    float4* o4 = (float4*)d_out;

    int rows  = in_sizes[0] / T;       // B*C = 4096
    int total = rows * T4;             // threads = 8,388,608
    int block = 256;
    int grid  = (total + block - 1) / block;

    TemporalUnfold1d_kernel<<<grid, block, 0, stream>>>(x4, o4, rows);
}